// Round 1
// baseline (594.357 us; speedup 1.0000x reference)
//
#include <hip/hip_runtime.h>
#include <hip/hip_bf16.h>
#include <math.h>
#include <stdint.h>

// Problem constants
#define CCH   192      // channels
#define HWD   224      // H = W = 224
#define NWIN  8192     // 8 * 32 * 32 windows
#define NPIX  49       // 7*7 pixels per window
#define MPAD  64       // padded M for MFMA
#define KDIM  192      // GEMM1 K
#define NHEAD 6
#define HD    32

typedef __bf16 bf16x8 __attribute__((ext_vector_type(8)));
typedef float f32x4 __attribute__((ext_vector_type(4)));

__device__ __forceinline__ uint16_t f2bf(float f) {
    uint32_t u = __builtin_bit_cast(uint32_t, f);
    u += 0x7FFFu + ((u >> 16) & 1u);   // RNE (inputs finite)
    return (uint16_t)(u >> 16);
}

__global__ void wconv_kernel(const float* __restrict__ w,
                             uint16_t* __restrict__ wbf, int n) {
    int i = blockIdx.x * 256 + threadIdx.x;
    if (i < n) wbf[i] = f2bf(w[i]);
}

// One block per window. 256 threads = 4 waves.
__global__ __launch_bounds__(256, 2)
void attn_win_kernel(const float* __restrict__ x,
                     const uint16_t* __restrict__ wbf,
                     const float* __restrict__ bq,
                     float* __restrict__ out) {
    // ldsA: xw tile (bf16, swizzled), later reused for q. ldsB: k.
    __shared__ uint16_t ldsA[MPAD * KDIM];
    __shared__ uint16_t ldsB[MPAD * KDIM];

    const int tid  = threadIdx.x;
    const int wave = tid >> 6;
    const int l    = tid & 63;
    const int lg   = l >> 4;    // lane group 0..3
    const int lr   = l & 15;    // lane row/col 0..15

    // XCD-bijective remap: each XCD gets one contiguous batch image (8192 % 8 == 0)
    const int win = ((blockIdx.x & 7) << 10) | (blockIdx.x >> 3);
    const int b  = win >> 10;
    const int wh = (win >> 5) & 31;
    const int ww = win & 31;
    const int h0 = wh * 7, w0 = ww * 7;

    // ---- Phase 1: zero pad rows 49..63, load x window -> ldsA (bf16, swizzled)
    {
        uint32_t* za = (uint32_t*)ldsA;
        #pragma unroll
        for (int o = tid; o < (MPAD - NPIX) * (KDIM / 2); o += 256)
            za[NPIX * (KDIM / 2) + o] = 0u;
    }
    {
        const float* xb = x + (size_t)b * CCH * HWD * HWD;
        for (int idx = tid; idx < NPIX * CCH; idx += 256) {
            int c = idx / NPIX;
            int n = idx - c * NPIX;
            int r = n / 7, s = n - r * 7;
            float v = xb[((size_t)c * HWD + (h0 + r)) * HWD + (w0 + s)];
            int byte = (n * (KDIM * 2) + c * 2) ^ ((n & 7) << 4);
            *(uint16_t*)((char*)ldsA + byte) = f2bf(v);
        }
    }
    __syncthreads();

    // ---- Phase 2: GEMM1  qk[64 x 384] = xw @ W^T   (wave owns 96 cols)
    f32x4 acc[4][6];
    #pragma unroll
    for (int mt = 0; mt < 4; ++mt)
        #pragma unroll
        for (int nt = 0; nt < 6; ++nt)
            acc[mt][nt] = f32x4{0.f, 0.f, 0.f, 0.f};

    #pragma unroll
    for (int kk = 0; kk < 6; ++kk) {
        bf16x8 afr[4];
        #pragma unroll
        for (int mt = 0; mt < 4; ++mt) {
            int row = mt * 16 + lr;
            int byte = (row * (KDIM * 2) + kk * 64 + lg * 16) ^ ((row & 7) << 4);
            afr[mt] = *(const bf16x8*)((const char*)ldsA + byte);
        }
        #pragma unroll
        for (int nt = 0; nt < 6; ++nt) {
            int col = wave * 96 + nt * 16 + lr;
            bf16x8 bfr = *(const bf16x8*)(wbf + col * KDIM + kk * 32 + lg * 8);
            #pragma unroll
            for (int mt = 0; mt < 4; ++mt)
                acc[mt][nt] = __builtin_amdgcn_mfma_f32_16x16x32_bf16(
                    afr[mt], bfr, acc[mt][nt], 0, 0, 0);
        }
    }
    __syncthreads();   // all GEMM1 reads of ldsA done before q overwrites it

    // ---- Phase 3: bias (+scale for q), store q -> ldsA, k -> ldsB as bf16
    {
        const float scale = 0.17677669529663687f;  // 32^-0.5
        const bool isq = (wave < 2);
        const float mul = isq ? scale : 1.0f;
        uint16_t* dst = isq ? ldsA : ldsB;
        #pragma unroll
        for (int nt = 0; nt < 6; ++nt) {
            int col = wave * 96 + nt * 16 + lr;
            float bias = bq[col];
            int jj = isq ? col : (col - 192);
            #pragma unroll
            for (int mt = 0; mt < 4; ++mt) {
                #pragma unroll
                for (int r = 0; r < 4; ++r) {
                    int row = mt * 16 + lg * 4 + r;
                    float v = (acc[mt][nt][r] + bias) * mul;
                    int byte = (row * (KDIM * 2) + jj * 2) ^ ((row & 7) << 4);
                    *(uint16_t*)((char*)dst + byte) = f2bf(v);
                }
            }
        }
    }
    __syncthreads();

    // ---- Phase 4: GEMM2 (q_h @ k_h^T) + softmax + store.
    // 24 (head, mtile) pairs, 6 per wave.
    float* outw = out + (size_t)win * (NHEAD * NPIX * NPIX);
    #pragma unroll
    for (int i = 0; i < 6; ++i) {
        const int p  = wave * 6 + i;
        const int h  = p >> 2;
        const int mt = p & 3;

        const int arow = mt * 16 + lr;
        const int abyte = (arow * (KDIM * 2) + h * 64 + lg * 16) ^ ((arow & 7) << 4);
        const bf16x8 afr = *(const bf16x8*)((const char*)ldsA + abyte);

        f32x4 pacc[4];
        #pragma unroll
        for (int nt2 = 0; nt2 < 4; ++nt2) {
            int brow = nt2 * 16 + lr;
            int bbyte = (brow * (KDIM * 2) + h * 64 + lg * 16) ^ ((brow & 7) << 4);
            bf16x8 bfr = *(const bf16x8*)((const char*)ldsB + bbyte);
            pacc[nt2] = __builtin_amdgcn_mfma_f32_16x16x32_bf16(
                afr, bfr, f32x4{0.f, 0.f, 0.f, 0.f}, 0, 0, 0);
        }

        // softmax over cols (m). Row n = mt*16 + lg*4 + r; lane holds cols nt2*16+lr.
        #pragma unroll
        for (int r = 0; r < 4; ++r) {
            float v[4];
            #pragma unroll
            for (int nt2 = 0; nt2 < 4; ++nt2) {
                int cc = nt2 * 16 + lr;
                v[nt2] = (cc < NPIX) ? pacc[nt2][r] : -INFINITY;
            }
            float m = fmaxf(fmaxf(v[0], v[1]), fmaxf(v[2], v[3]));
            #pragma unroll
            for (int s = 1; s < 16; s <<= 1)
                m = fmaxf(m, __shfl_xor(m, s, 64));

            float e[4];
            float sum = 0.f;
            #pragma unroll
            for (int nt2 = 0; nt2 < 4; ++nt2) {
                e[nt2] = __expf(v[nt2] - m);   // exp(-inf)=0 for masked cols
                sum += e[nt2];
            }
            #pragma unroll
            for (int s = 1; s < 16; s <<= 1)
                sum += __shfl_xor(sum, s, 64);
            float inv = 1.0f / sum;

            int n = mt * 16 + lg * 4 + r;
            if (n < NPIX) {
                float* orow = outw + (size_t)h * (NPIX * NPIX) + (size_t)n * NPIX;
                #pragma unroll
                for (int nt2 = 0; nt2 < 4; ++nt2) {
                    int cc = nt2 * 16 + lr;
                    if (cc < NPIX) orow[cc] = e[nt2] * inv;
                }
            }
        }
    }
}

extern "C" void kernel_launch(void* const* d_in, const int* in_sizes, int n_in,
                              void* d_out, int out_size, void* d_ws, size_t ws_size,
                              hipStream_t stream) {
    const float* x  = (const float*)d_in[0];
    const float* W  = (const float*)d_in[1];
    const float* bq = (const float*)d_in[2];
    float* out = (float*)d_out;
    uint16_t* wbf = (uint16_t*)d_ws;   // 384*192 bf16 = 147456 B

    wconv_kernel<<<(384 * 192 + 255) / 256, 256, 0, stream>>>(W, wbf, 384 * 192);
    attn_win_kernel<<<NWIN, 256, 0, stream>>>(x, wbf, bq, out);
}